// Round 1
// baseline (5351.297 us; speedup 1.0000x reference)
//
#include <hip/hip_runtime.h>
#include <stdint.h>

// SelfRNN: 4-layer tanh RNN, SEQ=256, B=64, H=512.
// Persistent-kernel design: weights resident in VGPRs, 128 workgroups
// (4 layers x 4 batch-groups x 8 col-groups), flag-based P2P sync.

#define SEQ 256
#define BB  64
#define HH  512
#define NL  4
#define GM  4          // batch groups of 16 rows
#define GN  8          // column groups of 64 cols (16 per wave)
#define WGT 256        // threads per workgroup (4 waves)
#define LDS_STRIDE 1032  // 1024 + 8 shorts pad (16B) -> conflict-benign b128 reads

typedef __attribute__((ext_vector_type(8))) short bf16x8;
typedef __attribute__((ext_vector_type(4))) float f32x4;

__device__ inline short f2bf(float f){
  uint32_t u = __builtin_bit_cast(uint32_t, f);
  u += 0x7fffu + ((u >> 16) & 1u);   // round-to-nearest-even
  return (short)(u >> 16);
}

__device__ inline float fast_tanh(float xv){
  xv = fminf(15.0f, fmaxf(-15.0f, xv));
  float e = __expf(2.0f * xv);
  return (e - 1.0f) / (e + 1.0f);
}

__device__ inline void spin_ge(int* f, int target){
  int it = 0;
  while (__hip_atomic_load(f, __ATOMIC_ACQUIRE, __HIP_MEMORY_SCOPE_AGENT) < target){
    __builtin_amdgcn_s_sleep(1);
    if (++it > (1 << 28)) break;   // bailout: wrong-but-terminating beats hang
  }
}

// Zero sync flags (every call: d_ws is re-poisoned 0xAA) and optionally
// convert x to bf16 shadow.
__global__ void rnn_prep(const float* __restrict__ x, short* __restrict__ xbf,
                         int* __restrict__ flags, int usews){
  int bid = blockIdx.x, tid = threadIdx.x;
  if (bid == 0){
    for (int k = tid; k < SEQ*NL*GM; k += WGT) flags[k] = 0;
  }
  if (usews && bid >= 1){
    long base = ((long)(bid - 1) * WGT + tid) * 8;  // 4096 blocks cover 8.39M elems
    f32x4 a = *(const f32x4*)(x + base);
    f32x4 b = *(const f32x4*)(x + base + 4);
    bf16x8 s;
    s[0]=f2bf(a[0]); s[1]=f2bf(a[1]); s[2]=f2bf(a[2]); s[3]=f2bf(a[3]);
    s[4]=f2bf(b[0]); s[5]=f2bf(b[1]); s[6]=f2bf(b[2]); s[7]=f2bf(b[3]);
    *(bf16x8*)(xbf + base) = s;
  }
}

__global__ __launch_bounds__(WGT, 1)
void rnn_main(const float* __restrict__ x,
              const float* __restrict__ w_ih, const float* __restrict__ b_ih,
              const float* __restrict__ w_hh, const float* __restrict__ b_hh,
              float* __restrict__ out,
              short* __restrict__ xbf, short* __restrict__ actbf,
              int* __restrict__ flags, int usews)
{
  const int tid  = threadIdx.x;
  const int wv   = tid >> 6;
  const int lane = tid & 63;
  const int bid  = blockIdx.x;
  // bid = n*16 + i*4 + m  -> each (i,m) family of 8 producers shares an XCD (bid%8 const)
  const int n = bid >> 4;
  const int i = (bid >> 2) & 3;
  const int m = bid & 3;

  const int l15  = lane & 15;
  const int lq   = lane >> 4;            // quarter-wave 0..3
  const int jcol = n*64 + wv*16 + l15;   // this wave's 16 output cols
  const int ksub = lq * 8;

  __shared__ short lA[16 * LDS_STRIDE];  // A tile [16 rows][1024 k] bf16, padded

  // ---- persistent weight fragments: B-operand, [16 cols x 1024 k] per wave ----
  // fragment kk covers k in [kk*32, kk*32+32); kk<16 -> w_ih (k=inp), kk>=16 -> w_hh (k=h)
  bf16x8 wf[32];
  {
    const float* wih = w_ih + (long)i*HH*HH + (long)jcol*HH;
    const float* whh = w_hh + (long)i*HH*HH + (long)jcol*HH;
    #pragma unroll
    for (int kk = 0; kk < 16; ++kk){
      const float* p = wih + kk*32 + ksub;
      f32x4 a = *(const f32x4*)p, b = *(const f32x4*)(p + 4);
      bf16x8 s;
      s[0]=f2bf(a[0]); s[1]=f2bf(a[1]); s[2]=f2bf(a[2]); s[3]=f2bf(a[3]);
      s[4]=f2bf(b[0]); s[5]=f2bf(b[1]); s[6]=f2bf(b[2]); s[7]=f2bf(b[3]);
      wf[kk] = s;
      const float* q = whh + kk*32 + ksub;
      f32x4 c = *(const f32x4*)q, d = *(const f32x4*)(q + 4);
      bf16x8 u;
      u[0]=f2bf(c[0]); u[1]=f2bf(c[1]); u[2]=f2bf(c[2]); u[3]=f2bf(c[3]);
      u[4]=f2bf(d[0]); u[5]=f2bf(d[1]); u[6]=f2bf(d[2]); u[7]=f2bf(d[3]);
      wf[kk + 16] = u;
    }
  }
  const float bsum = b_ih[(long)i*HH + jcol] + b_hh[(long)i*HH + jcol];

  float* states = out + (long)SEQ*BB*HH;   // all_states region: [(t*4+i)][b][h]
  const int bg0 = m * 16;

  for (int t = 0; t < SEQ; ++t){
    // ---- wait for producers: prev layer @ t, own layer family @ t-1 ----
    if (tid == 0){
      if (i > 0) spin_ge(&flags[(t*NL + (i-1))*GM + m], GN);
      if (t > 0) spin_ge(&flags[((t-1)*NL + i)*GM + m], GN);
    }
    __syncthreads();
    __builtin_amdgcn_fence(__ATOMIC_ACQUIRE, "agent");  // invalidate stale L1/L2

    // ---- stage A = [inp(512) | h(512)] rows bg0..bg0+15 into LDS as bf16 ----
    #pragma unroll
    for (int c = 0; c < 8; ++c){
      int chunk = c * WGT + tid;          // 2048 chunks of 8 elems
      int row   = chunk >> 7;
      int col0  = (chunk & 127) * 8;
      int bg    = bg0 + row;
      bool ish  = (col0 >= HH);
      if (!(ish && t == 0)){              // t==0: h=0, skip (MFMAs skipped too)
        bf16x8 s;
        if (usews){
          const short* src;
          if (!ish) src = (i == 0) ? xbf   + ((long)t*BB + bg)*HH + col0
                                   : actbf + ((long)(t*NL + (i-1))*BB + bg)*HH + col0;
          else      src = actbf + ((long)((t-1)*NL + i)*BB + bg)*HH + (col0 - HH);
          s = *(const bf16x8*)src;
        } else {
          const float* src;
          if (!ish) src = (i == 0) ? x      + ((long)t*BB + bg)*HH + col0
                                   : states + ((long)(t*NL + (i-1))*BB + bg)*HH + col0;
          else      src = states + ((long)((t-1)*NL + i)*BB + bg)*HH + (col0 - HH);
          f32x4 a = *(const f32x4*)src, b = *(const f32x4*)(src + 4);
          s[0]=f2bf(a[0]); s[1]=f2bf(a[1]); s[2]=f2bf(a[2]); s[3]=f2bf(a[3]);
          s[4]=f2bf(b[0]); s[5]=f2bf(b[1]); s[6]=f2bf(b[2]); s[7]=f2bf(b[3]);
        }
        *(bf16x8*)(lA + row*LDS_STRIDE + col0) = s;
      }
    }
    __syncthreads();

    // ---- MFMA: out[16 rows x 16 cols], K=1024 (512 at t==0) ----
    f32x4 acc = {0.f, 0.f, 0.f, 0.f};
    const short* arow = lA + l15*LDS_STRIDE + ksub;
    #pragma unroll
    for (int kk = 0; kk < 16; ++kk)
      acc = __builtin_amdgcn_mfma_f32_16x16x32_bf16(*(const bf16x8*)(arow + kk*32), wf[kk], acc, 0, 0, 0);
    if (t > 0){
      #pragma unroll
      for (int kk = 16; kk < 32; ++kk)
        acc = __builtin_amdgcn_mfma_f32_16x16x32_bf16(*(const bf16x8*)(arow + kk*32), wf[kk], acc, 0, 0, 0);
    }

    // ---- epilogue: bias + tanh, write states (+outputs for last layer) ----
    #pragma unroll
    for (int r = 0; r < 4; ++r){
      float v = fast_tanh(acc[r] + bsum);   // C/D: col=lane&15, row=lq*4+r (m89-verified)
      int brow = lq*4 + r;
      long srow = (long)(t*NL + i)*BB + bg0 + brow;
      states[srow*HH + jcol] = v;
      if (i == NL-1) out[((long)t*BB + bg0 + brow)*HH + jcol] = v;
      if (usews) actbf[srow*HH + jcol] = f2bf(v);
    }

    __threadfence();          // drain + make writes agent-visible before flag
    __syncthreads();          // all threads' fences complete
    if (tid == 0) atomicAdd(&flags[(t*NL + i)*GM + m], 1);  // device-scope
  }
}

extern "C" void kernel_launch(void* const* d_in, const int* in_sizes, int n_in,
                              void* d_out, int out_size, void* d_ws, size_t ws_size,
                              hipStream_t stream)
{
  (void)in_sizes; (void)n_in; (void)out_size;
  const float* x    = (const float*)d_in[0];
  const float* w_ih = (const float*)d_in[1];
  const float* b_ih = (const float*)d_in[2];
  const float* w_hh = (const float*)d_in[3];
  const float* b_hh = (const float*)d_in[4];
  float* out = (float*)d_out;

  // ws layout: [0,16K) flags | [16K, 16K+16.8M) x_bf16 | then acts_bf16 (67.1MB)
  const size_t X_OFF     = 16384;
  const size_t XBF_BYTES = (size_t)SEQ*BB*HH*2;
  const size_t ACT_OFF   = X_OFF + XBF_BYTES;
  const size_t ACT_BYTES = (size_t)SEQ*NL*BB*HH*2;
  int usews = (ws_size >= ACT_OFF + ACT_BYTES) ? 1 : 0;

  int*   flags = (int*)d_ws;
  short* xbf   = (short*)((char*)d_ws + X_OFF);
  short* actbf = (short*)((char*)d_ws + ACT_OFF);

  int prep_blocks = usews ? (1 + SEQ*BB*HH/(WGT*8)) : 1;   // 4097 or 1
  hipLaunchKernelGGL(rnn_prep, dim3(prep_blocks), dim3(WGT), 0, stream,
                     x, xbf, flags, usews);
  hipLaunchKernelGGL(rnn_main, dim3(NL*GM*GN), dim3(WGT), 0, stream,
                     x, w_ih, b_ih, w_hh, b_hh, out, xbf, actbf, flags, usews);
}

// Round 2
// 2161.693 us; speedup vs baseline: 2.4755x; 2.4755x over previous
//
#include <hip/hip_runtime.h>
#include <stdint.h>

// SelfRNN: 4-layer tanh RNN, SEQ=256, B=64, H=512.
// Persistent-kernel design: weights resident in VGPRs, 128 workgroups
// (4 layers x 4 batch-groups x 8 col-groups), flag-based P2P sync.
// R2: relaxed polling (no buffer_inv per poll), single-thread fences,
//     non-temporal bulk stores, 64B-padded flags.

#define SEQ 256
#define BB  64
#define HH  512
#define NL  4
#define GM  4          // batch groups of 16 rows
#define GN  8          // column groups of 64 cols (16 per wave)
#define WGT 256        // threads per workgroup (4 waves)
#define LDS_STRIDE 1032  // 1024 + 8 shorts pad (16B) -> conflict-benign b128 reads
#define FLAG_STRIDE 16   // 16 ints = 64B per flag -> no false sharing at coherence point
#define FIDX(t,i,m) ((((t)*NL + (i))*GM + (m)) * FLAG_STRIDE)

typedef __attribute__((ext_vector_type(8))) short bf16x8;
typedef __attribute__((ext_vector_type(4))) float f32x4;

__device__ inline short f2bf(float f){
  uint32_t u = __builtin_bit_cast(uint32_t, f);
  u += 0x7fffu + ((u >> 16) & 1u);   // round-to-nearest-even
  return (short)(u >> 16);
}

__device__ inline float fast_tanh(float xv){
  xv = fminf(15.0f, fmaxf(-15.0f, xv));
  float e = __expf(2.0f * xv);
  return (e - 1.0f) / (e + 1.0f);
}

// RELAXED agent-scope poll: emits an sc-flagged load to the coherence point
// each iteration but NO buffer_inv (the acquire fence after the spin does
// cache maintenance exactly once).
__device__ inline void spin_ge(int* f, int target){
  int it = 0;
  while (__hip_atomic_load(f, __ATOMIC_RELAXED, __HIP_MEMORY_SCOPE_AGENT) < target){
    __builtin_amdgcn_s_sleep(1);
    if (++it > (1 << 28)) break;   // bailout: wrong-but-terminating beats hang
  }
}

// Zero sync flags (every call: d_ws is re-poisoned 0xAA) and optionally
// convert x to bf16 shadow.
__global__ void rnn_prep(const float* __restrict__ x, short* __restrict__ xbf,
                         int* __restrict__ flags, int usews){
  int bid = blockIdx.x, tid = threadIdx.x;
  if (bid == 0){
    for (int k = tid; k < SEQ*NL*GM*FLAG_STRIDE; k += WGT) flags[k] = 0;
  }
  if (usews && bid >= 1){
    long base = ((long)(bid - 1) * WGT + tid) * 8;  // 4096 blocks cover 8.39M elems
    f32x4 a = *(const f32x4*)(x + base);
    f32x4 b = *(const f32x4*)(x + base + 4);
    bf16x8 s;
    s[0]=f2bf(a[0]); s[1]=f2bf(a[1]); s[2]=f2bf(a[2]); s[3]=f2bf(a[3]);
    s[4]=f2bf(b[0]); s[5]=f2bf(b[1]); s[6]=f2bf(b[2]); s[7]=f2bf(b[3]);
    *(bf16x8*)(xbf + base) = s;
  }
}

__global__ __launch_bounds__(WGT, 1)
void rnn_main(const float* __restrict__ x,
              const float* __restrict__ w_ih, const float* __restrict__ b_ih,
              const float* __restrict__ w_hh, const float* __restrict__ b_hh,
              float* __restrict__ out,
              short* __restrict__ xbf, short* __restrict__ actbf,
              int* __restrict__ flags, int usews)
{
  const int tid  = threadIdx.x;
  const int wv   = tid >> 6;
  const int lane = tid & 63;
  const int bid  = blockIdx.x;
  const int n = bid >> 4;
  const int i = (bid >> 2) & 3;
  const int m = bid & 3;

  const int l15  = lane & 15;
  const int lq   = lane >> 4;            // quarter-wave 0..3
  const int jcol = n*64 + wv*16 + l15;   // this wave's 16 output cols
  const int ksub = lq * 8;

  __shared__ short lA[16 * LDS_STRIDE];  // A tile [16 rows][1024 k] bf16, padded

  // ---- persistent weight fragments: B-operand, [16 cols x 1024 k] per wave ----
  bf16x8 wf[32];
  {
    const float* wih = w_ih + (long)i*HH*HH + (long)jcol*HH;
    const float* whh = w_hh + (long)i*HH*HH + (long)jcol*HH;
    #pragma unroll
    for (int kk = 0; kk < 16; ++kk){
      const float* p = wih + kk*32 + ksub;
      f32x4 a = *(const f32x4*)p, b = *(const f32x4*)(p + 4);
      bf16x8 s;
      s[0]=f2bf(a[0]); s[1]=f2bf(a[1]); s[2]=f2bf(a[2]); s[3]=f2bf(a[3]);
      s[4]=f2bf(b[0]); s[5]=f2bf(b[1]); s[6]=f2bf(b[2]); s[7]=f2bf(b[3]);
      wf[kk] = s;
      const float* q = whh + kk*32 + ksub;
      f32x4 c = *(const f32x4*)q, d = *(const f32x4*)(q + 4);
      bf16x8 u;
      u[0]=f2bf(c[0]); u[1]=f2bf(c[1]); u[2]=f2bf(c[2]); u[3]=f2bf(c[3]);
      u[4]=f2bf(d[0]); u[5]=f2bf(d[1]); u[6]=f2bf(d[2]); u[7]=f2bf(d[3]);
      wf[kk + 16] = u;
    }
  }
  const float bsum = b_ih[(long)i*HH + jcol] + b_hh[(long)i*HH + jcol];

  float* states = out + (long)SEQ*BB*HH;   // all_states region: [(t*4+i)][b][h]
  const int bg0 = m * 16;

  for (int t = 0; t < SEQ; ++t){
    // ---- wait for producers: prev layer @ t, own layer family @ t-1 ----
    if (tid == 0){
      if (i > 0) spin_ge(&flags[FIDX(t, i-1, m)], GN);
      if (t > 0) spin_ge(&flags[FIDX(t-1, i, m)], GN);
      // ONE acquire fence per WG-step: L1 is per-CU (shared by our 4 waves),
      // L2 per-XCD -> tid0's buffer_inv covers all threads' later loads
      // (they issue after the barrier below).
      if (i > 0 || t > 0) __builtin_amdgcn_fence(__ATOMIC_ACQUIRE, "agent");
    }
    __syncthreads();

    // ---- stage A = [inp(512) | h(512)] rows bg0..bg0+15 into LDS as bf16 ----
    #pragma unroll
    for (int c = 0; c < 8; ++c){
      int chunk = c * WGT + tid;          // 2048 chunks of 8 elems
      int row   = chunk >> 7;
      int col0  = (chunk & 127) * 8;
      int bg    = bg0 + row;
      bool ish  = (col0 >= HH);
      if (!(ish && t == 0)){              // t==0: h=0, skip (MFMAs skipped too)
        bf16x8 s;
        if (usews){
          const short* src;
          if (!ish) src = (i == 0) ? xbf   + ((long)t*BB + bg)*HH + col0
                                   : actbf + ((long)(t*NL + (i-1))*BB + bg)*HH + col0;
          else      src = actbf + ((long)((t-1)*NL + i)*BB + bg)*HH + (col0 - HH);
          s = *(const bf16x8*)src;
        } else {
          const float* src;
          if (!ish) src = (i == 0) ? x      + ((long)t*BB + bg)*HH + col0
                                   : states + ((long)(t*NL + (i-1))*BB + bg)*HH + col0;
          else      src = states + ((long)((t-1)*NL + i)*BB + bg)*HH + (col0 - HH);
          f32x4 a = *(const f32x4*)src, b = *(const f32x4*)(src + 4);
          s[0]=f2bf(a[0]); s[1]=f2bf(a[1]); s[2]=f2bf(a[2]); s[3]=f2bf(a[3]);
          s[4]=f2bf(b[0]); s[5]=f2bf(b[1]); s[6]=f2bf(b[2]); s[7]=f2bf(b[3]);
        }
        *(bf16x8*)(lA + row*LDS_STRIDE + col0) = s;
      }
    }
    __syncthreads();

    // ---- MFMA: out[16 rows x 16 cols], K=1024 (512 at t==0) ----
    f32x4 acc = {0.f, 0.f, 0.f, 0.f};
    const short* arow = lA + l15*LDS_STRIDE + ksub;
    #pragma unroll
    for (int kk = 0; kk < 16; ++kk)
      acc = __builtin_amdgcn_mfma_f32_16x16x32_bf16(*(const bf16x8*)(arow + kk*32), wf[kk], acc, 0, 0, 0);
    if (t > 0){
      #pragma unroll
      for (int kk = 16; kk < 32; ++kk)
        acc = __builtin_amdgcn_mfma_f32_16x16x32_bf16(*(const bf16x8*)(arow + kk*32), wf[kk], acc, 0, 0, 0);
    }

    // ---- epilogue: bias + tanh; non-temporal stores keep L2 clean so the
    //      per-step release wbl2 has little to flush ----
    #pragma unroll
    for (int r = 0; r < 4; ++r){
      float v = fast_tanh(acc[r] + bsum);   // C/D: col=lane&15, row=lq*4+r (m89-verified)
      int brow = lq*4 + r;
      long srow = (long)(t*NL + i)*BB + bg0 + brow;
      __builtin_nontemporal_store(v, states + srow*HH + jcol);
      if (i == NL-1) __builtin_nontemporal_store(v, out + ((long)t*BB + bg0 + brow)*HH + jcol);
      if (usews) __builtin_nontemporal_store(f2bf(v), actbf + srow*HH + jcol);
    }

    // __syncthreads drains every wave's stores to L2 (vmcnt(0) before
    // s_barrier); then ONE release fence (wbl2) + flag add by tid0.
    __syncthreads();
    if (tid == 0){
      __builtin_amdgcn_fence(__ATOMIC_RELEASE, "agent");
      __hip_atomic_fetch_add(&flags[FIDX(t, i, m)], 1,
                             __ATOMIC_RELAXED, __HIP_MEMORY_SCOPE_AGENT);
    }
  }
}

extern "C" void kernel_launch(void* const* d_in, const int* in_sizes, int n_in,
                              void* d_out, int out_size, void* d_ws, size_t ws_size,
                              hipStream_t stream)
{
  (void)in_sizes; (void)n_in; (void)out_size;
  const float* x    = (const float*)d_in[0];
  const float* w_ih = (const float*)d_in[1];
  const float* b_ih = (const float*)d_in[2];
  const float* w_hh = (const float*)d_in[3];
  const float* b_hh = (const float*)d_in[4];
  float* out = (float*)d_out;

  // ws layout: [0,256K) flags (64B-padded) | [256K, +16.8M) x_bf16 | acts_bf16 (67.1MB)
  const size_t FLAGS_BYTES = (size_t)SEQ*NL*GM*FLAG_STRIDE*4;  // 256 KB
  const size_t X_OFF     = FLAGS_BYTES;
  const size_t XBF_BYTES = (size_t)SEQ*BB*HH*2;
  const size_t ACT_OFF   = X_OFF + XBF_BYTES;
  const size_t ACT_BYTES = (size_t)SEQ*NL*BB*HH*2;
  int usews = (ws_size >= ACT_OFF + ACT_BYTES) ? 1 : 0;

  int*   flags = (int*)d_ws;
  short* xbf   = (short*)((char*)d_ws + X_OFF);
  short* actbf = (short*)((char*)d_ws + ACT_OFF);

  int prep_blocks = usews ? (1 + SEQ*BB*HH/(WGT*8)) : 1;   // 4097 or 1
  hipLaunchKernelGGL(rnn_prep, dim3(prep_blocks), dim3(WGT), 0, stream,
                     x, xbf, flags, usews);
  hipLaunchKernelGGL(rnn_main, dim3(NL*GM*GN), dim3(WGT), 0, stream,
                     x, w_ih, b_ih, w_hh, b_hh, out, xbf, actbf, flags, usews);
}